// Round 3
// baseline (572.195 us; speedup 1.0000x reference)
//
#include <hip/hip_runtime.h>
#include <hip/hip_bf16.h>

#define N0_  320000
#define N1_  80000
#define N2_  16000
#define INC_ 128
#define HID_ 64
#define H1_  4
#define C1_  256   // H1*HID
#define OUT_ 48
#define OUTP_ 64   // padded layer-2 feature stride
#define NEG_ 0.2f

typedef __attribute__((ext_vector_type(8))) short bfrag8;   // 8 bf16 (4 VGPRs)
typedef __attribute__((ext_vector_type(4))) float ffrag4;   // 4 fp32 acc

__device__ __forceinline__ float bf2f(unsigned short u){
  unsigned int v = ((unsigned int)u) << 16;
  return __uint_as_float(v);
}
__device__ __forceinline__ unsigned short f2bf(float f){
  unsigned int u = __float_as_uint(f);
  u += 0x7FFFu + ((u >> 16) & 1u);   // round-to-nearest-even
  return (unsigned short)(u >> 16);
}
__device__ __forceinline__ void unpack2(unsigned int u, float& lo, float& hi){
  lo = __uint_as_float(u << 16);
  hi = __uint_as_float(u & 0xffff0000u);
}

// ---- all 4 weight transposes in one kernel (f32 [K][N] -> bf16 [N][K]) ----
__global__ void transpose_all(const float* __restrict__ Wl1, const float* __restrict__ Wr1,
                              const float* __restrict__ Wl2, const float* __restrict__ Wr2,
                              unsigned short* __restrict__ Wt1l, unsigned short* __restrict__ Wt1r,
                              unsigned short* __restrict__ Wt2l, unsigned short* __restrict__ Wt2r){
  int idx = blockIdx.x*256 + threadIdx.x;
  if (idx < 32768){ int n = idx >> 7, k = idx & 127; Wt1l[idx] = f2bf(Wl1[k*C1_ + n]); }
  else if (idx < 65536){ int j = idx - 32768; int n = j >> 7, k = j & 127; Wt1r[j] = f2bf(Wr1[k*C1_ + n]); }
  else if (idx < 77824){ int j = idx - 65536; int n = j >> 8, k = j & 255; Wt2l[j] = f2bf(Wl2[k*OUT_ + n]); }
  else if (idx < 90112){ int j = idx - 77824; int n = j >> 8, k = j & 255; Wt2r[j] = f2bf(Wr2[k*OUT_ + n]); }
}

// ------- fused GEMM1 v4: 512 threads / 8 waves per 64-row tile, acc[2][4] per wave -------
// JOURNAL:
//  R0 (108.7us): 256thr, acc[4][4]+bfr[4][4] ~= 84 arch + 64 acc = 148 regs/wave
//     -> hard 3 waves/SIMD, Occ 29.5%, latency-bound at 2.64 TB/s.
//  R1 FAILED: __launch_bounds__(256,4) cap 128 -> arch squeezed to 64, spills (+50MB traffic).
//  R2 FAILED: +pf[8] prefetch (32 regs) at (256,3) -> spills again (+30MB), 124.6us.
//  Lesson: VGPR_Count hides the acc-reg half; per-wave STATE must shrink to raise occupancy.
//  v4: wave owns 32rows x 64cols -> acc[2][4]=32 acc regs; B frags reloaded per-ks (bk[4],
//  16 regs, L2-resident 64KB slab) instead of held 64. Peak ~100 regs < 128 cap at
//  (512,4) -> no spills, 16 waves/CU (was 12), half the serial MFMA chain per wave.
__global__ __launch_bounds__(512, 4) void gemm1_fused(
    const float* __restrict__ X,
    const unsigned short* __restrict__ Wtl, const unsigned short* __restrict__ Wtr,
    const float* __restrict__ bl, const float* __restrict__ br,
    unsigned short* __restrict__ outl, unsigned short* __restrict__ outr)
{
  __shared__ unsigned short As[64][136];   // +8 pad: 2-way bank aliasing only (free)
  __shared__ unsigned short Cs[32][264];   // half-height epilogue bounce
  const int t = threadIdx.x;               // 0..511
  const int lane = t & 63, wave = t >> 6;  // 8 waves
  const int rh = wave >> 2;                // row half (32 rows)
  const int cg = wave & 3;                 // col group (64 cols)
  const int row0 = blockIdx.x << 6;
  const int l15 = lane & 15, q = lane >> 4;
  const int wcol = cg << 6;

  // stage 64x128 f32 -> bf16: 2048 float4 / 512 threads = 4 each
  #pragma unroll
  for (int i = 0; i < 4; ++i){
    int idx = (i<<9) + t;
    int r = idx >> 5, c4 = idx & 31;
    float4 xv = *(const float4*)(X + ((size_t)(row0 + r) << 7) + (c4<<2));
    ushort4 s; s.x=f2bf(xv.x); s.y=f2bf(xv.y); s.z=f2bf(xv.z); s.w=f2bf(xv.w);
    *(ushort4*)(&As[r][c4<<2]) = s;
  }
  __syncthreads();

  const int npass = (row0 < N1_) ? 2 : 1;  // N1 = 1250*64 -> uniform per block
  for (int pass = 0; pass < npass; ++pass){
    const unsigned short* Wt = pass ? Wtr : Wtl;
    const float* bias = pass ? br : bl;
    unsigned short* out = pass ? outr : outl;

    ffrag4 z = {0.f, 0.f, 0.f, 0.f};
    ffrag4 acc[2][4];
    #pragma unroll
    for (int mtl = 0; mtl < 2; ++mtl)
      #pragma unroll
      for (int nt = 0; nt < 4; ++nt) acc[mtl][nt] = z;

    #pragma unroll
    for (int ks = 0; ks < 4; ++ks){
      bfrag8 bk[4];
      #pragma unroll
      for (int nt = 0; nt < 4; ++nt)
        bk[nt] = *(const bfrag8*)(Wt + (size_t)(wcol + (nt<<4) + l15)*128 + (ks<<5) + (q<<3));
      #pragma unroll
      for (int mtl = 0; mtl < 2; ++mtl){
        bfrag8 af = *(const bfrag8*)(&As[(rh<<5) + (mtl<<4) + l15][(ks<<5) + (q<<3)]);
        #pragma unroll
        for (int nt = 0; nt < 4; ++nt)
          acc[mtl][nt] = __builtin_amdgcn_mfma_f32_16x16x32_bf16(af, bk[nt], acc[mtl][nt], 0, 0, 0);
      }
    }

    float bb[4];
    #pragma unroll
    for (int nt = 0; nt < 4; ++nt) bb[nt] = bias[wcol + (nt<<4) + l15];

    // epilogue: two 32-row halves through Cs; waves with rh==hg produce, all copy out
    #pragma unroll
    for (int hg = 0; hg < 2; ++hg){
      __syncthreads();                  // Cs free (covers prior copy-out / prior pass)
      if (rh == hg){
        #pragma unroll
        for (int mtl = 0; mtl < 2; ++mtl)
          #pragma unroll
          for (int nt = 0; nt < 4; ++nt)
            #pragma unroll
            for (int rg = 0; rg < 4; ++rg)
              Cs[(mtl<<4) + (q<<2) + rg][wcol + (nt<<4) + l15] = f2bf(acc[mtl][nt][rg] + bb[nt]);
      }
      __syncthreads();
      #pragma unroll
      for (int i = 0; i < 2; ++i){      // 32x256 bf16 = 1024 bfrag8 / 512 thr
        int idx = (i<<9) + t;
        int r = idx >> 5, c = (idx & 31) << 3;
        *(bfrag8*)(out + ((size_t)(row0 + (hg<<5) + r) << 8) + c) = *(const bfrag8*)(&Cs[r][c]);
      }
    }
  }
}

// ------- fused GEMM2: [M,256] bf16 @ Wt2[48][256] + b -> f32 [M][64] zero-padded -------
__global__ __launch_bounds__(256) void gemm2_fused(
    const unsigned short* __restrict__ Hin,
    const unsigned short* __restrict__ Wtl, const unsigned short* __restrict__ Wtr,
    const float* __restrict__ bl, const float* __restrict__ br,
    float* __restrict__ outl, float* __restrict__ outr)
{
  __shared__ unsigned short As2[64][264];
  __shared__ unsigned short Bs2[48][264];
  const int t = threadIdx.x;
  const int lane = t & 63, wave = t >> 6;
  const int row0 = blockIdx.x << 6;
  const int l15 = lane & 15, q = lane >> 4;
  const int c32 = t & 31;

  #pragma unroll
  for (int i = 0; i < 8; ++i){
    int r = (i<<3) + (t>>5);
    *(bfrag8*)(&As2[r][c32<<3]) = *(const bfrag8*)(Hin + ((size_t)(row0 + r) << 8) + (c32<<3));
  }

  const int npass = (row0 < N2_) ? 2 : 1;
  for (int pass = 0; pass < npass; ++pass){
    const unsigned short* Wt = pass ? Wtr : Wtl;
    const float* bias = pass ? br : bl;
    float* out = pass ? outr : outl;

    if (pass) __syncthreads();          // prior mfma done before Bs2 overwrite
    #pragma unroll
    for (int i = 0; i < 6; ++i){
      int idx = i*256 + t;
      int r = idx >> 5, c = (idx & 31) << 3;
      *(bfrag8*)(&Bs2[r][c]) = *(const bfrag8*)(Wt + (size_t)r*256 + c);
    }
    __syncthreads();                    // also covers As2 staging on pass 0

    ffrag4 z = {0.f, 0.f, 0.f, 0.f};
    ffrag4 acc[3] = {z, z, z};
    #pragma unroll
    for (int ks = 0; ks < 8; ++ks){
      bfrag8 af = *(const bfrag8*)(&As2[(wave<<4) + l15][(ks<<5) + (q<<3)]);
      #pragma unroll
      for (int nt = 0; nt < 3; ++nt){
        bfrag8 bf = *(const bfrag8*)(&Bs2[(nt<<4) + l15][(ks<<5) + (q<<3)]);
        acc[nt] = __builtin_amdgcn_mfma_f32_16x16x32_bf16(af, bf, acc[nt], 0, 0, 0);
      }
    }
    #pragma unroll
    for (int nt = 0; nt < 3; ++nt){
      int col = (nt<<4) + l15;
      float bb = bias[col];
      #pragma unroll
      for (int rg = 0; rg < 4; ++rg){
        int row = row0 + (wave<<4) + (q<<2) + rg;
        out[(size_t)row*OUTP_ + col] = acc[nt][rg] + bb;
      }
    }
    #pragma unroll
    for (int rg = 0; rg < 4; ++rg){     // zero pad cols 48..63
      int row = row0 + (wave<<4) + (q<<2) + rg;
      out[(size_t)row*OUTP_ + 48 + l15] = 0.f;
    }
  }
}

// ---------------- CSR build (both edge sets per kernel) ----------------
__global__ void hist_both(const int* __restrict__ dst1, const int* __restrict__ dst2,
                          int* __restrict__ cnt1, int* __restrict__ cnt2, int E1, int E2){
  int i = blockIdx.x*256 + threadIdx.x;
  if (i < E1) atomicAdd(&cnt1[dst1[i]], 1);
  else if (i < E1 + E2) atomicAdd(&cnt2[dst2[i - E1]], 1);
}

__global__ __launch_bounds__(256) void scan_local_both(
    const int* __restrict__ in1, const int* __restrict__ in2,
    int* __restrict__ ex1, int* __restrict__ ex2,
    int* __restrict__ part1, int* __restrict__ part2, int n1, int n2, int nb1){
  __shared__ int s[256];
  const int* in; int* excl; int* partials; int n; int b;
  if ((int)blockIdx.x < nb1){ in = in1; excl = ex1; partials = part1; n = n1; b = blockIdx.x; }
  else { in = in2; excl = ex2; partials = part2; n = n2; b = blockIdx.x - nb1; }
  int t = threadIdx.x, i = b*256 + t;
  int v = (i < n) ? in[i] : 0;
  s[t] = v; __syncthreads();
  #pragma unroll
  for (int off = 1; off < 256; off <<= 1){
    int u = (t >= off) ? s[t-off] : 0;
    __syncthreads();
    s[t] += u; __syncthreads();
  }
  if (i < n) excl[i] = s[t] - v;
  if (t == 255) partials[b] = s[255];
}

__global__ __launch_bounds__(512) void scan_partials_both(
    int* __restrict__ part1, int* __restrict__ part2, int nb1, int nb2){
  __shared__ int s[512];
  int* partials = blockIdx.x ? part2 : part1;
  int nb = blockIdx.x ? nb2 : nb1;
  int t = threadIdx.x;
  int v = (t < nb) ? partials[t] : 0;
  s[t] = v; __syncthreads();
  #pragma unroll
  for (int off = 1; off < 512; off <<= 1){
    int u = (t >= off) ? s[t-off] : 0;
    __syncthreads();
    s[t] += u; __syncthreads();
  }
  if (t < nb) partials[t] = s[t] - v;
}

__global__ void scan_finalize_both(
    int* __restrict__ ex1, int* __restrict__ ex2,
    const int* __restrict__ part1, const int* __restrict__ part2,
    int* __restrict__ cur1, int* __restrict__ cur2, int n1, int n2, int nb1){
  int* excl; const int* partials; int* cursor; int n; int b;
  if ((int)blockIdx.x < nb1){ excl = ex1; partials = part1; cursor = cur1; n = n1; b = blockIdx.x; }
  else { excl = ex2; partials = part2; cursor = cur2; n = n2; b = blockIdx.x - nb1; }
  int i = b*256 + threadIdx.x;
  if (i >= n) return;
  int o = excl[i] + partials[b];
  excl[i] = o; cursor[i] = o;
}

__global__ void scatter_both(const int* __restrict__ src1, const int* __restrict__ dst1,
                             const int* __restrict__ src2, const int* __restrict__ dst2,
                             int* __restrict__ cur1, int* __restrict__ cur2,
                             int* __restrict__ perm1, int* __restrict__ perm2, int E1, int E2){
  int i = blockIdx.x*256 + threadIdx.x;
  if (i < E1){
    int pos = atomicAdd(&cur1[dst1[i]], 1);
    perm1[pos] = src1[i];
  } else if (i < E1 + E2){
    int j = i - E1;
    int pos = atomicAdd(&cur2[dst2[j]], 1);
    perm2[pos] = src2[j];
  }
}

// ---------- fused layer-1 aggregation: wave/node, 2 edges/iter, 1-ahead gather prefetch ----------
__global__ __launch_bounds__(256) void gat_aggregate1(
    const unsigned short* __restrict__ xl, const unsigned short* __restrict__ xr,
    const int* __restrict__ offsets, const int* __restrict__ counts,
    const int* __restrict__ perm, const float* __restrict__ att,
    const float* __restrict__ bias, unsigned short* __restrict__ hout, int n)
{
  int node = (blockIdx.x << 2) + (threadIdx.x >> 6);
  if (node >= n) return;
  const int lane = threadIdx.x & 63;
  const int slot = lane >> 5;          // edge parity
  const int sub  = lane & 31;
  const int elem = sub << 3;           // 8 channels per lane (head = sub>>3)
  const unsigned int ebyte = (unsigned)elem << 1;
  const char* xlb = (const char*)xl;

  const int st = offsets[node], cnt = counts[node];
  uint4 ru = *(const uint4*)(xr + ((size_t)node << 8) + elem);
  float r[8];
  unpack2(ru.x, r[0], r[1]); unpack2(ru.y, r[2], r[3]);
  unpack2(ru.z, r[4], r[5]); unpack2(ru.w, r[6], r[7]);
  float4 al = *(const float4*)(att + elem);
  float4 ah = *(const float4*)(att + elem + 4);
  float a[8] = {al.x, al.y, al.z, al.w, ah.x, ah.y, ah.z, ah.w};

  float acc[8] = {0,0,0,0,0,0,0,0};
  float den = 0.f;

  for (int jb = 0; jb < cnt; jb += 64){
    int m = cnt - jb; if (m > 64) m = 64;
    int pv = (lane < m) ? perm[st + jb + lane] : 0;
    int s_cur = __shfl(pv, slot);
    uint4 xc = *(const uint4*)(xlb + (((unsigned)s_cur << 9) + ebyte));
    for (int j = 0; j < m; j += 2){
      int s_next = __shfl(pv, (j + 2 + slot) & 63);     // out-of-range -> pv=0 lanes (safe)
      uint4 xn = *(const uint4*)(xlb + (((unsigned)s_next << 9) + ebyte));  // prefetch j+2
      float x[8];
      unpack2(xc.x, x[0], x[1]); unpack2(xc.y, x[2], x[3]);
      unpack2(xc.z, x[4], x[5]); unpack2(xc.w, x[6], x[7]);
      float p = 0.f;
      #pragma unroll
      for (int i = 0; i < 8; ++i){
        float v = x[i] + r[i];
        float e = fmaf(NEG_, fminf(v, 0.f), fmaxf(v, 0.f));
        p = fmaf(e, a[i], p);
      }
      p += __shfl_xor(p, 1);
      p += __shfl_xor(p, 2);
      p += __shfl_xor(p, 4);         // full 64-ch head dot on all 8 lanes
      float ex = __expf(p);          // |alpha| bounded -> native exp safe
      ex = (j + slot < m) ? ex : 0.f;
      den += ex;
      #pragma unroll
      for (int i = 0; i < 8; ++i) acc[i] = fmaf(ex, x[i], acc[i]);
      xc = xn;
    }
  }
  den += __shfl_xor(den, 32);
  #pragma unroll
  for (int i = 0; i < 8; ++i) acc[i] += __shfl_xor(acc[i], 32);

  if (slot == 0){
    float w = 1.f / (den + 1e-16f);
    float4 bl = *(const float4*)(bias + elem);
    float4 bh = *(const float4*)(bias + elem + 4);
    float b[8] = {bl.x, bl.y, bl.z, bl.w, bh.x, bh.y, bh.z, bh.w};
    unsigned int o[4];
    #pragma unroll
    for (int i = 0; i < 4; ++i){
      unsigned short lo = f2bf(fmaxf(fmaf(acc[2*i],   w, b[2*i]),   0.f));
      unsigned short hi = f2bf(fmaxf(fmaf(acc[2*i+1], w, b[2*i+1]), 0.f));
      o[i] = (unsigned)lo | ((unsigned)hi << 16);
    }
    *(uint4*)(hout + ((size_t)node << 8) + elem) = make_uint4(o[0], o[1], o[2], o[3]);
  }
}

// ---------- fused layer-2 aggregation + log_softmax: wave/node, 4 edges/iter, prefetch ----------
__global__ __launch_bounds__(256) void gat_aggregate2(
    const float* __restrict__ xl, const float* __restrict__ xr,   // padded [.,64]
    const int* __restrict__ offsets, const int* __restrict__ counts,
    const int* __restrict__ perm, const float* __restrict__ att,
    const float* __restrict__ bias, float* __restrict__ out, int n)
{
  int node = (blockIdx.x << 2) + (threadIdx.x >> 6);
  if (node >= n) return;
  const int lane = threadIdx.x & 63;
  const int slot = lane >> 4;          // 0..3
  const int sub  = lane & 15;          // 4 channels (pad beyond 48)
  const bool realc = sub < 12;

  const int st = offsets[node], cnt = counts[node];
  float4 r = *(const float4*)(xr + (size_t)node*OUTP_ + (sub<<2));   // pads are 0
  float4 a = realc ? *(const float4*)(att + (sub<<2)) : make_float4(0,0,0,0);
  float4 acc = make_float4(0,0,0,0);
  float den = 0.f;

  for (int jb = 0; jb < cnt; jb += 64){
    int m = cnt - jb; if (m > 64) m = 64;
    int pv = (lane < m) ? perm[st + jb + lane] : 0;
    int s_cur = __shfl(pv, slot);
    float4 xc = *(const float4*)(xl + (size_t)((unsigned)s_cur*OUTP_ + (sub<<2)));
    for (int j = 0; j < m; j += 4){
      int s_next = __shfl(pv, (j + 4 + slot) & 63);
      float4 xn = *(const float4*)(xl + (size_t)((unsigned)s_next*OUTP_ + (sub<<2)));
      float v0 = xc.x + r.x, v1 = xc.y + r.y, v2 = xc.z + r.z, v3 = xc.w + r.w;
      float p;
      p = fmaf(a.x, fmaf(NEG_, fminf(v0,0.f), fmaxf(v0,0.f)), 0.f);
      p = fmaf(a.y, fmaf(NEG_, fminf(v1,0.f), fmaxf(v1,0.f)), p);
      p = fmaf(a.z, fmaf(NEG_, fminf(v2,0.f), fmaxf(v2,0.f)), p);
      p = fmaf(a.w, fmaf(NEG_, fminf(v3,0.f), fmaxf(v3,0.f)), p);
      p += __shfl_xor(p, 1);
      p += __shfl_xor(p, 2);
      p += __shfl_xor(p, 4);
      p += __shfl_xor(p, 8);
      float ex = __expf(p);
      ex = (j + slot < m) ? ex : 0.f;
      den += ex;
      acc.x = fmaf(ex, xc.x, acc.x); acc.y = fmaf(ex, xc.y, acc.y);
      acc.z = fmaf(ex, xc.z, acc.z); acc.w = fmaf(ex, xc.w, acc.w);
      xc = xn;
    }
  }
  den += __shfl_xor(den, 16); den += __shfl_xor(den, 32);
  acc.x += __shfl_xor(acc.x, 16); acc.x += __shfl_xor(acc.x, 32);
  acc.y += __shfl_xor(acc.y, 16); acc.y += __shfl_xor(acc.y, 32);
  acc.z += __shfl_xor(acc.z, 16); acc.z += __shfl_xor(acc.z, 32);
  acc.w += __shfl_xor(acc.w, 16); acc.w += __shfl_xor(acc.w, 32);

  float w = 1.f / (den + 1e-16f);
  float4 b = realc ? *(const float4*)(bias + (sub<<2)) : make_float4(0,0,0,0);
  float v0 = fmaf(acc.x, w, b.x), v1 = fmaf(acc.y, w, b.y);
  float v2 = fmaf(acc.z, w, b.z), v3 = fmaf(acc.w, w, b.w);

  float mx = realc ? fmaxf(fmaxf(v0, v1), fmaxf(v2, v3)) : -3.0e38f;
  mx = fmaxf(mx, __shfl_xor(mx, 1)); mx = fmaxf(mx, __shfl_xor(mx, 2));
  mx = fmaxf(mx, __shfl_xor(mx, 4)); mx = fmaxf(mx, __shfl_xor(mx, 8));
  float es = realc ? (__expf(v0-mx) + __expf(v1-mx) + __expf(v2-mx) + __expf(v3-mx)) : 0.f;
  es += __shfl_xor(es, 1); es += __shfl_xor(es, 2);
  es += __shfl_xor(es, 4); es += __shfl_xor(es, 8);
  float ls = __logf(es);
  if (slot == 0 && realc){
    float4 o = make_float4(v0-mx-ls, v1-mx-ls, v2-mx-ls, v3-mx-ls);
    *(float4*)(out + (size_t)node*OUT_ + (sub<<2)) = o;
  }
}

extern "C" void kernel_launch(void* const* d_in, const int* in_sizes, int n_in,
                              void* d_out, int out_size, void* d_ws, size_t ws_size,
                              hipStream_t stream)
{
  const float* x    = (const float*)d_in[0];
  const float* Wl1  = (const float*)d_in[1];
  const float* bl1  = (const float*)d_in[2];
  const float* Wr1  = (const float*)d_in[3];
  const float* br1  = (const float*)d_in[4];
  const float* att1 = (const float*)d_in[5];
  const float* bias1= (const float*)d_in[6];
  const float* Wl2  = (const float*)d_in[7];
  const float* bl2  = (const float*)d_in[8];
  const float* Wr2  = (const float*)d_in[9];
  const float* br2  = (const float*)d_in[10];
  const float* att2 = (const float*)d_in[11];
  const float* bias2= (const float*)d_in[12];
  const int* src1 = (const int*)d_in[13];
  const int* dst1 = (const int*)d_in[14];
  const int* src2 = (const int*)d_in[15];
  const int* dst2 = (const int*)d_in[16];
  const int E1 = in_sizes[13];
  const int E2 = in_sizes[15];
  (void)n_in; (void)out_size; (void)ws_size;

  // ---- workspace layout (bytes), total ~275.5 MB ----
  char* ws = (char*)d_ws;
  unsigned short* xl1  = (unsigned short*)(ws + 0LL);          // bf16 [320000][256]
  unsigned short* xr1  = (unsigned short*)(ws + 163840000LL);  // bf16 [ 80000][256]
  unsigned short* hbuf = (unsigned short*)(ws + 204800000LL);  // bf16 [ 80000][256]
  float* xl2p   = (float*)(ws + 245760000LL);                  // f32  [ 80000][64] padded
  float* xr2p   = (float*)(ws + 266240000LL);                  // f32  [ 16000][64] padded
  int*   perm1  = (int*)  (ws + 270336000LL);                  // int  [800000]
  int*   perm2  = (int*)  (ws + 273536000LL);                  // int  [160000]
  int*   cnt1   = (int*)  (ws + 274176000LL);                  // int  [ 80000] (zeroed)
  int*   cnt2   = (int*)  (ws + 274496000LL);                  // int  [ 16000] (zeroed)
  int*   off1   = (int*)  (ws + 274560000LL);                  // int  [ 80000]
  int*   cur1   = (int*)  (ws + 274880000LL);                  // int  [ 80000]
  int*   off2   = (int*)  (ws + 275200000LL);                  // int  [ 16000]
  int*   cur2   = (int*)  (ws + 275264000LL);                  // int  [ 16000]
  int*   part1  = (int*)  (ws + 275328000LL);                  // int  [   512]
  int*   part2  = (int*)  (ws + 275330048LL);                  // int  [   512]
  unsigned short* Wt1l = (unsigned short*)(ws + 275332096LL);  // bf16 [256][128]
  unsigned short* Wt1r = (unsigned short*)(ws + 275397632LL);  // bf16 [256][128]
  unsigned short* Wt2l = (unsigned short*)(ws + 275463168LL);  // bf16 [ 48][256]
  unsigned short* Wt2r = (unsigned short*)(ws + 275487744LL);  // bf16 [ 48][256]

  hipMemsetAsync(ws + 274176000LL, 0, 384000LL, stream);       // cnt1 + cnt2

  const int nb1 = (N1_ + 255) / 256;   // 313
  const int nb2 = (N2_ + 255) / 256;   // 63

  transpose_all<<<352, 256, 0, stream>>>(Wl1, Wr1, Wl2, Wr2, Wt1l, Wt1r, Wt2l, Wt2r);

  // CSR build for both edge sets (independent of GEMMs)
  hist_both         <<<(E1+E2+255)/256, 256, 0, stream>>>(dst1, dst2, cnt1, cnt2, E1, E2);
  scan_local_both   <<<nb1+nb2, 256, 0, stream>>>(cnt1, cnt2, off1, off2, part1, part2, N1_, N2_, nb1);
  scan_partials_both<<<2, 512, 0, stream>>>(part1, part2, nb1, nb2);
  scan_finalize_both<<<nb1+nb2, 256, 0, stream>>>(off1, off2, part1, part2, cur1, cur2, N1_, N2_, nb1);
  scatter_both      <<<(E1+E2+255)/256, 256, 0, stream>>>(src1, dst1, src2, dst2,
                                                          cur1, cur2, perm1, perm2, E1, E2);

  gemm1_fused<<<N0_/64, 512, 0, stream>>>(x, Wt1l, Wt1r, bl1, br1, xl1, xr1);

  gat_aggregate1<<<(N1_+3)/4, 256, 0, stream>>>(xl1, xr1, off1, cnt1, perm1,
                                                att1, bias1, hbuf, N1_);

  gemm2_fused<<<N1_/64, 256, 0, stream>>>(hbuf, Wt2l, Wt2r, bl2, br2, xl2p, xr2p);

  gat_aggregate2<<<(N2_+3)/4, 256, 0, stream>>>(xl2p, xr2p, off2, cnt2, perm2,
                                                att2, bias2, (float*)d_out, N2_);
}

// Round 4
// 538.259 us; speedup vs baseline: 1.0630x; 1.0630x over previous
//
#include <hip/hip_runtime.h>
#include <hip/hip_bf16.h>

#define N0_  320000
#define N1_  80000
#define N2_  16000
#define INC_ 128
#define HID_ 64
#define H1_  4
#define C1_  256   // H1*HID
#define OUT_ 48
#define OUTP_ 64   // padded layer-2 feature stride
#define NEG_ 0.2f

typedef __attribute__((ext_vector_type(8))) short bfrag8;   // 8 bf16 (4 VGPRs)
typedef __attribute__((ext_vector_type(4))) float ffrag4;   // 4 fp32 acc

__device__ __forceinline__ float bf2f(unsigned short u){
  unsigned int v = ((unsigned int)u) << 16;
  return __uint_as_float(v);
}
__device__ __forceinline__ unsigned short f2bf(float f){
  unsigned int u = __float_as_uint(f);
  u += 0x7FFFu + ((u >> 16) & 1u);   // round-to-nearest-even
  return (unsigned short)(u >> 16);
}
__device__ __forceinline__ void unpack2(unsigned int u, float& lo, float& hi){
  lo = __uint_as_float(u << 16);
  hi = __uint_as_float(u & 0xffff0000u);
}

// ---- all 4 weight transposes in one kernel (f32 [K][N] -> bf16 [N][K]) ----
__global__ void transpose_all(const float* __restrict__ Wl1, const float* __restrict__ Wr1,
                              const float* __restrict__ Wl2, const float* __restrict__ Wr2,
                              unsigned short* __restrict__ Wt1l, unsigned short* __restrict__ Wt1r,
                              unsigned short* __restrict__ Wt2l, unsigned short* __restrict__ Wt2r){
  int idx = blockIdx.x*256 + threadIdx.x;
  if (idx < 32768){ int n = idx >> 7, k = idx & 127; Wt1l[idx] = f2bf(Wl1[k*C1_ + n]); }
  else if (idx < 65536){ int j = idx - 32768; int n = j >> 7, k = j & 127; Wt1r[j] = f2bf(Wr1[k*C1_ + n]); }
  else if (idx < 77824){ int j = idx - 65536; int n = j >> 8, k = j & 255; Wt2l[j] = f2bf(Wl2[k*OUT_ + n]); }
  else if (idx < 90112){ int j = idx - 77824; int n = j >> 8, k = j & 255; Wt2r[j] = f2bf(Wr2[k*OUT_ + n]); }
}

// ------- fused GEMM1 (R0-exact, 108.7us measured): stage A once; 2 passes -------
// JOURNAL of failed restructures (keep for future sessions):
//  R1: __launch_bounds__(256,4) -> reg cap 128 < acc(64)+bfr(64)+addr state -> spills,
//      FETCH +52MB scratch, 133us.
//  R2: +pf[8] f32 prefetch of next tile at (256,3) -> spills again (+30MB), 124.6us.
//  R3: 512thr/8 waves, acc[2][4], bk[4] reloaded per-ks: NO spills, Occ 29.5->42.5%,
//      traffic identical — yet 148us. More waves lost to broken ILP: per-ks L2 B-loads
//      serialize with MFMAs at 56 VGPRs. Occupancy is NOT this kernel's constraint;
//      the hoisted bfr[4][4] ILP is. This structure at 3 blocks/CU is the local optimum.
__global__ __launch_bounds__(256, 3) void gemm1_fused(
    const float* __restrict__ X,
    const unsigned short* __restrict__ Wtl, const unsigned short* __restrict__ Wtr,
    const float* __restrict__ bl, const float* __restrict__ br,
    unsigned short* __restrict__ outl, unsigned short* __restrict__ outr)
{
  __shared__ unsigned short As[64][136];   // +8 pad: 2-way bank aliasing only (free)
  __shared__ unsigned short Cs[64][264];   // epilogue bounce for coalesced stores
  const int t = threadIdx.x;
  const int lane = t & 63, wave = t >> 6;
  const int row0 = blockIdx.x << 6;
  const int l15 = lane & 15, q = lane >> 4;
  const int wcol = wave << 6;
  const int c4 = t & 31;

  #pragma unroll
  for (int i = 0; i < 8; ++i){
    int r = (i<<3) + (t>>5);
    float4 xv = *(const float4*)(X + ((size_t)(row0 + r) << 7) + (c4<<2));
    ushort4 s; s.x=f2bf(xv.x); s.y=f2bf(xv.y); s.z=f2bf(xv.z); s.w=f2bf(xv.w);
    *(ushort4*)(&As[r][c4<<2]) = s;
  }
  __syncthreads();

  const int npass = (row0 < N1_) ? 2 : 1;
  for (int pass = 0; pass < npass; ++pass){
    const unsigned short* Wt = pass ? Wtr : Wtl;
    const float* bias = pass ? br : bl;
    unsigned short* out = pass ? outr : outl;

    bfrag8 bfr[4][4];
    #pragma unroll
    for (int nt = 0; nt < 4; ++nt)
      #pragma unroll
      for (int ks = 0; ks < 4; ++ks)
        bfr[nt][ks] = *(const bfrag8*)(Wt + (size_t)(wcol + (nt<<4) + l15)*128 + (ks<<5) + (q<<3));

    ffrag4 z = {0.f, 0.f, 0.f, 0.f};
    ffrag4 acc[4][4];
    #pragma unroll
    for (int mt = 0; mt < 4; ++mt)
      #pragma unroll
      for (int nt = 0; nt < 4; ++nt) acc[mt][nt] = z;

    #pragma unroll
    for (int mt = 0; mt < 4; ++mt){
      #pragma unroll
      for (int ks = 0; ks < 4; ++ks){
        bfrag8 af = *(const bfrag8*)(&As[(mt<<4) + l15][(ks<<5) + (q<<3)]);
        #pragma unroll
        for (int nt = 0; nt < 4; ++nt)
          acc[mt][nt] = __builtin_amdgcn_mfma_f32_16x16x32_bf16(af, bfr[nt][ks], acc[mt][nt], 0, 0, 0);
      }
    }

    float bb[4];
    #pragma unroll
    for (int nt = 0; nt < 4; ++nt) bb[nt] = bias[wcol + (nt<<4) + l15];
    #pragma unroll
    for (int mt = 0; mt < 4; ++mt)
      #pragma unroll
      for (int nt = 0; nt < 4; ++nt)
        #pragma unroll
        for (int rg = 0; rg < 4; ++rg)
          Cs[(mt<<4) + (q<<2) + rg][wcol + (nt<<4) + l15] = f2bf(acc[mt][nt][rg] + bb[nt]);
    __syncthreads();
    #pragma unroll
    for (int i = 0; i < 8; ++i){
      int r = (i<<3) + (t>>5);
      *(bfrag8*)(out + ((size_t)(row0 + r) << 8) + (c4<<3)) = *(const bfrag8*)(&Cs[r][c4<<3]);
    }
    if (pass + 1 < npass) __syncthreads();   // protect Cs reuse
  }
}

// ------- fused GEMM2: [M,256] bf16 @ Wt2[48][256] + b -> f32 [M][64] zero-padded -------
__global__ __launch_bounds__(256) void gemm2_fused(
    const unsigned short* __restrict__ Hin,
    const unsigned short* __restrict__ Wtl, const unsigned short* __restrict__ Wtr,
    const float* __restrict__ bl, const float* __restrict__ br,
    float* __restrict__ outl, float* __restrict__ outr)
{
  __shared__ unsigned short As2[64][264];
  __shared__ unsigned short Bs2[48][264];
  const int t = threadIdx.x;
  const int lane = t & 63, wave = t >> 6;
  const int row0 = blockIdx.x << 6;
  const int l15 = lane & 15, q = lane >> 4;
  const int c32 = t & 31;

  #pragma unroll
  for (int i = 0; i < 8; ++i){
    int r = (i<<3) + (t>>5);
    *(bfrag8*)(&As2[r][c32<<3]) = *(const bfrag8*)(Hin + ((size_t)(row0 + r) << 8) + (c32<<3));
  }

  const int npass = (row0 < N2_) ? 2 : 1;
  for (int pass = 0; pass < npass; ++pass){
    const unsigned short* Wt = pass ? Wtr : Wtl;
    const float* bias = pass ? br : bl;
    float* out = pass ? outr : outl;

    if (pass) __syncthreads();          // prior mfma done before Bs2 overwrite
    #pragma unroll
    for (int i = 0; i < 6; ++i){
      int idx = i*256 + t;
      int r = idx >> 5, c = (idx & 31) << 3;
      *(bfrag8*)(&Bs2[r][c]) = *(const bfrag8*)(Wt + (size_t)r*256 + c);
    }
    __syncthreads();                    // also covers As2 staging on pass 0

    ffrag4 z = {0.f, 0.f, 0.f, 0.f};
    ffrag4 acc[3] = {z, z, z};
    #pragma unroll
    for (int ks = 0; ks < 8; ++ks){
      bfrag8 af = *(const bfrag8*)(&As2[(wave<<4) + l15][(ks<<5) + (q<<3)]);
      #pragma unroll
      for (int nt = 0; nt < 3; ++nt){
        bfrag8 bf = *(const bfrag8*)(&Bs2[(nt<<4) + l15][(ks<<5) + (q<<3)]);
        acc[nt] = __builtin_amdgcn_mfma_f32_16x16x32_bf16(af, bf, acc[nt], 0, 0, 0);
      }
    }
    #pragma unroll
    for (int nt = 0; nt < 3; ++nt){
      int col = (nt<<4) + l15;
      float bb = bias[col];
      #pragma unroll
      for (int rg = 0; rg < 4; ++rg){
        int row = row0 + (wave<<4) + (q<<2) + rg;
        out[(size_t)row*OUTP_ + col] = acc[nt][rg] + bb;
      }
    }
    #pragma unroll
    for (int rg = 0; rg < 4; ++rg){     // zero pad cols 48..63
      int row = row0 + (wave<<4) + (q<<2) + rg;
      out[(size_t)row*OUTP_ + 48 + l15] = 0.f;
    }
  }
}

// ---------------- CSR build: 3 kernels (was 5) ----------------
// R4 JOURNAL: replaced scan_local+scan_partials+scan_finalize with ONE kernel
// (block-local LDS scan + atomicAdd global cursor for block base). Node->range
// order becomes nondeterministic, but any disjoint packing is correct: aggregation
// only uses offsets[node]/counts[node], and within-node edge order was already
// nondeterministic via scatter atomics (absorbed by tolerance).
__global__ void hist_both(const int* __restrict__ dst1, const int* __restrict__ dst2,
                          int* __restrict__ cnt1, int* __restrict__ cnt2, int E1, int E2){
  int i = blockIdx.x*256 + threadIdx.x;
  if (i < E1) atomicAdd(&cnt1[dst1[i]], 1);
  else if (i < E1 + E2) atomicAdd(&cnt2[dst2[i - E1]], 1);
}

__global__ __launch_bounds__(256) void scan_atomic_both(
    const int* __restrict__ cnt1, const int* __restrict__ cnt2,
    int* __restrict__ off1, int* __restrict__ off2,
    int* __restrict__ cur1, int* __restrict__ cur2,
    int* __restrict__ gpair, int n1, int n2, int nb1){
  __shared__ int s[256];
  __shared__ int base_s;
  const int* in; int* off; int* cur; int* g; int n; int b;
  if ((int)blockIdx.x < nb1){ in = cnt1; off = off1; cur = cur1; g = gpair;     n = n1; b = blockIdx.x; }
  else                      { in = cnt2; off = off2; cur = cur2; g = gpair + 1; n = n2; b = blockIdx.x - nb1; }
  int t = threadIdx.x, i = b*256 + t;
  int v = (i < n) ? in[i] : 0;
  s[t] = v; __syncthreads();
  #pragma unroll
  for (int d = 1; d < 256; d <<= 1){
    int u = (t >= d) ? s[t-d] : 0;
    __syncthreads();
    s[t] += u; __syncthreads();
  }
  if (t == 255) base_s = atomicAdd(g, s[255]);   // claim this block's range
  __syncthreads();
  if (i < n){
    int o = s[t] - v + base_s;
    off[i] = o; cur[i] = o;
  }
}

__global__ void scatter_both(const int* __restrict__ src1, const int* __restrict__ dst1,
                             const int* __restrict__ src2, const int* __restrict__ dst2,
                             int* __restrict__ cur1, int* __restrict__ cur2,
                             int* __restrict__ perm1, int* __restrict__ perm2, int E1, int E2){
  int i = blockIdx.x*256 + threadIdx.x;
  if (i < E1){
    int pos = atomicAdd(&cur1[dst1[i]], 1);
    perm1[pos] = src1[i];
  } else if (i < E1 + E2){
    int j = i - E1;
    int pos = atomicAdd(&cur2[dst2[j]], 1);
    perm2[pos] = src2[j];
  }
}

// ---------- fused layer-1 aggregation: wave/node, 2 edges/iter, 1-ahead gather prefetch ----------
__global__ __launch_bounds__(256) void gat_aggregate1(
    const unsigned short* __restrict__ xl, const unsigned short* __restrict__ xr,
    const int* __restrict__ offsets, const int* __restrict__ counts,
    const int* __restrict__ perm, const float* __restrict__ att,
    const float* __restrict__ bias, unsigned short* __restrict__ hout, int n)
{
  int node = (blockIdx.x << 2) + (threadIdx.x >> 6);
  if (node >= n) return;
  const int lane = threadIdx.x & 63;
  const int slot = lane >> 5;          // edge parity
  const int sub  = lane & 31;
  const int elem = sub << 3;           // 8 channels per lane (head = sub>>3)
  const unsigned int ebyte = (unsigned)elem << 1;
  const char* xlb = (const char*)xl;

  const int st = offsets[node], cnt = counts[node];
  uint4 ru = *(const uint4*)(xr + ((size_t)node << 8) + elem);
  float r[8];
  unpack2(ru.x, r[0], r[1]); unpack2(ru.y, r[2], r[3]);
  unpack2(ru.z, r[4], r[5]); unpack2(ru.w, r[6], r[7]);
  float4 al = *(const float4*)(att + elem);
  float4 ah = *(const float4*)(att + elem + 4);
  float a[8] = {al.x, al.y, al.z, al.w, ah.x, ah.y, ah.z, ah.w};

  float acc[8] = {0,0,0,0,0,0,0,0};
  float den = 0.f;

  for (int jb = 0; jb < cnt; jb += 64){
    int m = cnt - jb; if (m > 64) m = 64;
    int pv = (lane < m) ? perm[st + jb + lane] : 0;
    int s_cur = __shfl(pv, slot);
    uint4 xc = *(const uint4*)(xlb + (((unsigned)s_cur << 9) + ebyte));
    for (int j = 0; j < m; j += 2){
      int s_next = __shfl(pv, (j + 2 + slot) & 63);     // out-of-range -> pv=0 lanes (safe)
      uint4 xn = *(const uint4*)(xlb + (((unsigned)s_next << 9) + ebyte));  // prefetch j+2
      float x[8];
      unpack2(xc.x, x[0], x[1]); unpack2(xc.y, x[2], x[3]);
      unpack2(xc.z, x[4], x[5]); unpack2(xc.w, x[6], x[7]);
      float p = 0.f;
      #pragma unroll
      for (int i = 0; i < 8; ++i){
        float v = x[i] + r[i];
        float e = fmaf(NEG_, fminf(v, 0.f), fmaxf(v, 0.f));
        p = fmaf(e, a[i], p);
      }
      p += __shfl_xor(p, 1);
      p += __shfl_xor(p, 2);
      p += __shfl_xor(p, 4);         // full 64-ch head dot on all 8 lanes
      float ex = __expf(p);          // |alpha| bounded -> native exp safe
      ex = (j + slot < m) ? ex : 0.f;
      den += ex;
      #pragma unroll
      for (int i = 0; i < 8; ++i) acc[i] = fmaf(ex, x[i], acc[i]);
      xc = xn;
    }
  }
  den += __shfl_xor(den, 32);
  #pragma unroll
  for (int i = 0; i < 8; ++i) acc[i] += __shfl_xor(acc[i], 32);

  if (slot == 0){
    float w = 1.f / (den + 1e-16f);
    float4 bl = *(const float4*)(bias + elem);
    float4 bh = *(const float4*)(bias + elem + 4);
    float b[8] = {bl.x, bl.y, bl.z, bl.w, bh.x, bh.y, bh.z, bh.w};
    unsigned int o[4];
    #pragma unroll
    for (int i = 0; i < 4; ++i){
      unsigned short lo = f2bf(fmaxf(fmaf(acc[2*i],   w, b[2*i]),   0.f));
      unsigned short hi = f2bf(fmaxf(fmaf(acc[2*i+1], w, b[2*i+1]), 0.f));
      o[i] = (unsigned)lo | ((unsigned)hi << 16);
    }
    *(uint4*)(hout + ((size_t)node << 8) + elem) = make_uint4(o[0], o[1], o[2], o[3]);
  }
}

// ---------- fused layer-2 aggregation + log_softmax: wave/node, 4 edges/iter, prefetch ----------
__global__ __launch_bounds__(256) void gat_aggregate2(
    const float* __restrict__ xl, const float* __restrict__ xr,   // padded [.,64]
    const int* __restrict__ offsets, const int* __restrict__ counts,
    const int* __restrict__ perm, const float* __restrict__ att,
    const float* __restrict__ bias, float* __restrict__ out, int n)
{
  int node = (blockIdx.x << 2) + (threadIdx.x >> 6);
  if (node >= n) return;
  const int lane = threadIdx.x & 63;
  const int slot = lane >> 4;          // 0..3
  const int sub  = lane & 15;          // 4 channels (pad beyond 48)
  const bool realc = sub < 12;

  const int st = offsets[node], cnt = counts[node];
  float4 r = *(const float4*)(xr + (size_t)node*OUTP_ + (sub<<2));   // pads are 0
  float4 a = realc ? *(const float4*)(att + (sub<<2)) : make_float4(0,0,0,0);
  float4 acc = make_float4(0,0,0,0);
  float den = 0.f;

  for (int jb = 0; jb < cnt; jb += 64){
    int m = cnt - jb; if (m > 64) m = 64;
    int pv = (lane < m) ? perm[st + jb + lane] : 0;
    int s_cur = __shfl(pv, slot);
    float4 xc = *(const float4*)(xl + (size_t)((unsigned)s_cur*OUTP_ + (sub<<2)));
    for (int j = 0; j < m; j += 4){
      int s_next = __shfl(pv, (j + 4 + slot) & 63);
      float4 xn = *(const float4*)(xl + (size_t)((unsigned)s_next*OUTP_ + (sub<<2)));
      float v0 = xc.x + r.x, v1 = xc.y + r.y, v2 = xc.z + r.z, v3 = xc.w + r.w;
      float p;
      p = fmaf(a.x, fmaf(NEG_, fminf(v0,0.f), fmaxf(v0,0.f)), 0.f);
      p = fmaf(a.y, fmaf(NEG_, fminf(v1,0.f), fmaxf(v1,0.f)), p);
      p = fmaf(a.z, fmaf(NEG_, fminf(v2,0.f), fmaxf(v2,0.f)), p);
      p = fmaf(a.w, fmaf(NEG_, fminf(v3,0.f), fmaxf(v3,0.f)), p);
      p += __shfl_xor(p, 1);
      p += __shfl_xor(p, 2);
      p += __shfl_xor(p, 4);
      p += __shfl_xor(p, 8);
      float ex = __expf(p);
      ex = (j + slot < m) ? ex : 0.f;
      den += ex;
      acc.x = fmaf(ex, xc.x, acc.x); acc.y = fmaf(ex, xc.y, acc.y);
      acc.z = fmaf(ex, xc.z, acc.z); acc.w = fmaf(ex, xc.w, acc.w);
      xc = xn;
    }
  }
  den += __shfl_xor(den, 16); den += __shfl_xor(den, 32);
  acc.x += __shfl_xor(acc.x, 16); acc.x += __shfl_xor(acc.x, 32);
  acc.y += __shfl_xor(acc.y, 16); acc.y += __shfl_xor(acc.y, 32);
  acc.z += __shfl_xor(acc.z, 16); acc.z += __shfl_xor(acc.z, 32);
  acc.w += __shfl_xor(acc.w, 16); acc.w += __shfl_xor(acc.w, 32);

  float w = 1.f / (den + 1e-16f);
  float4 b = realc ? *(const float4*)(bias + (sub<<2)) : make_float4(0,0,0,0);
  float v0 = fmaf(acc.x, w, b.x), v1 = fmaf(acc.y, w, b.y);
  float v2 = fmaf(acc.z, w, b.z), v3 = fmaf(acc.w, w, b.w);

  float mx = realc ? fmaxf(fmaxf(v0, v1), fmaxf(v2, v3)) : -3.0e38f;
  mx = fmaxf(mx, __shfl_xor(mx, 1)); mx = fmaxf(mx, __shfl_xor(mx, 2));
  mx = fmaxf(mx, __shfl_xor(mx, 4)); mx = fmaxf(mx, __shfl_xor(mx, 8));
  float es = realc ? (__expf(v0-mx) + __expf(v1-mx) + __expf(v2-mx) + __expf(v3-mx)) : 0.f;
  es += __shfl_xor(es, 1); es += __shfl_xor(es, 2);
  es += __shfl_xor(es, 4); es += __shfl_xor(es, 8);
  float ls = __logf(es);
  if (slot == 0 && realc){
    float4 o = make_float4(v0-mx-ls, v1-mx-ls, v2-mx-ls, v3-mx-ls);
    *(float4*)(out + (size_t)node*OUT_ + (sub<<2)) = o;
  }
}

extern "C" void kernel_launch(void* const* d_in, const int* in_sizes, int n_in,
                              void* d_out, int out_size, void* d_ws, size_t ws_size,
                              hipStream_t stream)
{
  const float* x    = (const float*)d_in[0];
  const float* Wl1  = (const float*)d_in[1];
  const float* bl1  = (const float*)d_in[2];
  const float* Wr1  = (const float*)d_in[3];
  const float* br1  = (const float*)d_in[4];
  const float* att1 = (const float*)d_in[5];
  const float* bias1= (const float*)d_in[6];
  const float* Wl2  = (const float*)d_in[7];
  const float* bl2  = (const float*)d_in[8];
  const float* Wr2  = (const float*)d_in[9];
  const float* br2  = (const float*)d_in[10];
  const float* att2 = (const float*)d_in[11];
  const float* bias2= (const float*)d_in[12];
  const int* src1 = (const int*)d_in[13];
  const int* dst1 = (const int*)d_in[14];
  const int* src2 = (const int*)d_in[15];
  const int* dst2 = (const int*)d_in[16];
  const int E1 = in_sizes[13];
  const int E2 = in_sizes[15];
  (void)n_in; (void)out_size; (void)ws_size;

  // ---- workspace layout (bytes), total ~275.5 MB ----
  char* ws = (char*)d_ws;
  unsigned short* xl1  = (unsigned short*)(ws + 0LL);          // bf16 [320000][256]
  unsigned short* xr1  = (unsigned short*)(ws + 163840000LL);  // bf16 [ 80000][256]
  unsigned short* hbuf = (unsigned short*)(ws + 204800000LL);  // bf16 [ 80000][256]
  float* xl2p   = (float*)(ws + 245760000LL);                  // f32  [ 80000][64] padded
  float* xr2p   = (float*)(ws + 266240000LL);                  // f32  [ 16000][64] padded
  int*   perm1  = (int*)  (ws + 270336000LL);                  // int  [800000]
  int*   perm2  = (int*)  (ws + 273536000LL);                  // int  [160000]
  int*   cnt1   = (int*)  (ws + 274176000LL);                  // int  [ 80000] (zeroed)
  int*   cnt2   = (int*)  (ws + 274496000LL);                  // int  [ 16000] (zeroed)
  int*   off1   = (int*)  (ws + 274560000LL);                  // int  [ 80000]
  int*   cur1   = (int*)  (ws + 274880000LL);                  // int  [ 80000]
  int*   off2   = (int*)  (ws + 275200000LL);                  // int  [ 16000]
  int*   cur2   = (int*)  (ws + 275264000LL);                  // int  [ 16000]
  int*   gpair  = (int*)  (ws + 275328000LL);                  // int  [     2] (zeroed)
  unsigned short* Wt1l = (unsigned short*)(ws + 275332096LL);  // bf16 [256][128]
  unsigned short* Wt1r = (unsigned short*)(ws + 275397632LL);  // bf16 [256][128]
  unsigned short* Wt2l = (unsigned short*)(ws + 275463168LL);  // bf16 [ 48][256]
  unsigned short* Wt2r = (unsigned short*)(ws + 275487744LL);  // bf16 [ 48][256]

  hipMemsetAsync(ws + 274176000LL, 0, 384000LL, stream);       // cnt1 + cnt2
  hipMemsetAsync(ws + 275328000LL, 0, 8LL, stream);            // gpair

  const int nb1 = (N1_ + 255) / 256;   // 313
  const int nb2 = (N2_ + 255) / 256;   // 63

  transpose_all<<<352, 256, 0, stream>>>(Wl1, Wr1, Wl2, Wr2, Wt1l, Wt1r, Wt2l, Wt2r);

  // CSR build for both edge sets (3 kernels; see scan_atomic_both journal note)
  hist_both       <<<(E1+E2+255)/256, 256, 0, stream>>>(dst1, dst2, cnt1, cnt2, E1, E2);
  scan_atomic_both<<<nb1+nb2, 256, 0, stream>>>(cnt1, cnt2, off1, off2, cur1, cur2,
                                                gpair, N1_, N2_, nb1);
  scatter_both    <<<(E1+E2+255)/256, 256, 0, stream>>>(src1, dst1, src2, dst2,
                                                        cur1, cur2, perm1, perm2, E1, E2);

  gemm1_fused<<<N0_/64, 256, 0, stream>>>(x, Wt1l, Wt1r, bl1, br1, xl1, xr1);

  gat_aggregate1<<<(N1_+3)/4, 256, 0, stream>>>(xl1, xr1, off1, cnt1, perm1,
                                                att1, bias1, hbuf, N1_);

  gemm2_fused<<<N1_/64, 256, 0, stream>>>(hbuf, Wt2l, Wt2r, bl2, br2, xl2p, xr2p);

  gat_aggregate2<<<(N2_+3)/4, 256, 0, stream>>>(xl2p, xr2p, off2, cnt2, perm2,
                                                att2, bias2, (float*)d_out, N2_);
}